// Round 6
// baseline (1033.487 us; speedup 1.0000x reference)
//
#include <hip/hip_runtime.h>

#define N_NODES 50000
#define N_EDGES 800000
#define N_GRAPHS 64
#define F 256        // F_IN == F_HID
#define F_OUT 128
#define G_DIM 768    // 3*F
#define SCAN_NB ((N_NODES + 255) / 256)   // 196
#define POOL_CHUNKS 16

typedef short short8 __attribute__((ext_vector_type(8)));
typedef short short4v __attribute__((ext_vector_type(4)));
typedef float float4v __attribute__((ext_vector_type(4)));

// ---- bf16 split helpers (RNE) ----
__device__ __forceinline__ unsigned short f2bf(float f) {
    unsigned int u = __float_as_uint(f);
    u += 0x7FFFu + ((u >> 16) & 1u);
    return (unsigned short)(u >> 16);
}
__device__ __forceinline__ float bf2f(unsigned short s) {
    return __uint_as_float(((unsigned int)s) << 16);
}

// ---- async global->LDS, 16B per lane; LDS dest = uniform base + lane*16 ----
__device__ __forceinline__ void gld_lds16(const void* gsrc, void* ldst) {
    __builtin_amdgcn_global_load_lds(
        (const __attribute__((address_space(1))) unsigned int*)gsrc,
        (__attribute__((address_space(3))) unsigned int*)ldst, 16, 0, 0);
}

// ---------------- degree count (int) ----------------
__global__ void count_deg(const int* __restrict__ dst, int* deg) {
    int e = blockIdx.x * blockDim.x + threadIdx.x;
    if (e < N_EDGES) atomicAdd(&deg[dst[e]], 1);
}

__global__ void compute_dinv(const int* __restrict__ deg, float* dinv) {
    int i = blockIdx.x * blockDim.x + threadIdx.x;
    if (i < N_NODES) dinv[i] = rsqrtf((float)(deg[i] + 1));   // +1 self-loop
}

// ---------------- 3-kernel exclusive scan over deg -> row_ptr ----------------
__global__ void scan_blocks(const int* __restrict__ deg, int* __restrict__ row_ptr,
                            int* __restrict__ block_tot) {
    __shared__ int sd[256];
    int t = threadIdx.x;
    int idx = blockIdx.x * 256 + t;
    int v = (idx < N_NODES) ? deg[idx] : 0;
    sd[t] = v;
    __syncthreads();
    for (int off = 1; off < 256; off <<= 1) {
        int a = (t >= off) ? sd[t - off] : 0;
        __syncthreads();
        sd[t] += a;
        __syncthreads();
    }
    if (idx < N_NODES) row_ptr[idx] = sd[t] - v;
    if (t == 255) block_tot[blockIdx.x] = sd[255];
}

__global__ void scan_totals(int* block_tot) {
    __shared__ int sd[256];
    int t = threadIdx.x;
    int v = (t < SCAN_NB) ? block_tot[t] : 0;
    sd[t] = v;
    __syncthreads();
    for (int off = 1; off < 256; off <<= 1) {
        int a = (t >= off) ? sd[t - off] : 0;
        __syncthreads();
        sd[t] += a;
        __syncthreads();
    }
    if (t < SCAN_NB) block_tot[t] = sd[t] - v;
}

__global__ void add_offsets(int* __restrict__ row_ptr, const int* __restrict__ block_tot) {
    int idx = blockIdx.x * 256 + threadIdx.x;
    if (idx < N_NODES) row_ptr[idx] += block_tot[blockIdx.x];
    if (idx == 0) row_ptr[N_NODES] = N_EDGES;
}

// ---------------- bucket edges into CSR order; store src idx + full norm ----------------
__global__ void bucket_edges(const int* __restrict__ src, const int* __restrict__ dst,
                             const float* __restrict__ dinv,
                             const int* __restrict__ row_ptr, int* __restrict__ cursor,
                             unsigned short* __restrict__ srcs16,
                             float* __restrict__ wnorm) {
    int e = blockIdx.x * blockDim.x + threadIdx.x;
    if (e < N_EDGES) {
        int d = dst[e];
        int s = src[e];
        int pos = row_ptr[d] + atomicAdd(&cursor[d], 1);
        srcs16[pos] = (unsigned short)s;           // N_NODES < 65536
        wnorm[pos]  = dinv[s] * dinv[d];
    }
}

// ---------------- casts ----------------
__global__ void cast_split(const float* __restrict__ A, short* __restrict__ hi,
                           short* __restrict__ lo, int n4) {
    int i = blockIdx.x * blockDim.x + threadIdx.x;
    if (i < n4) {
        float4 v = ((const float4*)A)[i];
        short4v h, l;
        h.x = (short)f2bf(v.x); l.x = (short)f2bf(v.x - bf2f(h.x));
        h.y = (short)f2bf(v.y); l.y = (short)f2bf(v.y - bf2f(h.y));
        h.z = (short)f2bf(v.z); l.z = (short)f2bf(v.z - bf2f(h.z));
        h.w = (short)f2bf(v.w); l.w = (short)f2bf(v.w - bf2f(h.w));
        ((short4v*)hi)[i] = h;
        ((short4v*)lo)[i] = l;
    }
}

// W [256][256] -> transposed hi/lo: Bt[n][k] = W[k][n]
__global__ void cast_w_t(const float* __restrict__ W, short* __restrict__ hi,
                         short* __restrict__ lo) {
    int n = blockIdx.x;    // 256
    int k = threadIdx.x;   // 256
    float v = W[k * 256 + n];
    unsigned short h = f2bf(v);
    hi[n * 256 + k] = (short)h;
    lo[n * 256 + k] = (short)f2bf(v - bf2f(h));
}

// ---------------- split-bf16 MFMA GEMM with LDS staging ----------------
#define BM 128
#define BN 128
#define BK 32
__global__ __launch_bounds__(256) void gemm_mfma(
        const short* __restrict__ Ahi, const short* __restrict__ Alo,
        const short* __restrict__ Bthi, const short* __restrict__ Btlo,
        float* __restrict__ C, int M) {
    __shared__ short sAh[BM * BK], sAl[BM * BK], sBh[BN * BK], sBl[BN * BK];
    int tid = threadIdx.x;
    int wave = tid >> 6, lane = tid & 63;
    int q = lane >> 4, t = lane & 15;
    int row0 = blockIdx.y * BM;
    int col0 = blockIdx.x * BN;
    int wr = (wave >> 1) * 64;
    int wc = (wave & 1) * 64;

    int lrow = lane >> 2;          // 0..15
    int lk = (lane & 3) * 8;       // k offset (shorts)
    int srow0 = wave * 32;

    float4v acc[4][4] = {};
    for (int kt = 0; kt < 256; kt += BK) {
#pragma unroll
        for (int half = 0; half < 2; ++half) {
            int r = srow0 + half * 16 + lrow;
            int ga = row0 + r; if (ga >= M) ga = M - 1;   // clamp; never stored
            size_t aoff = (size_t)ga * 256 + kt + lk;
            size_t boff = (size_t)(col0 + r) * 256 + kt + lk;
            int ldso = (srow0 + half * 16) * BK;
            gld_lds16(&Ahi[aoff], &sAh[ldso]);
            gld_lds16(&Alo[aoff], &sAl[ldso]);
            gld_lds16(&Bthi[boff], &sBh[ldso]);
            gld_lds16(&Btlo[boff], &sBl[ldso]);
        }
        __syncthreads();
        short8 ah[4], al[4], bh[4], bl[4];
#pragma unroll
        for (int mi = 0; mi < 4; ++mi) {
            int r = wr + mi * 16 + t;
            ah[mi] = *(const short8*)&sAh[r * BK + q * 8];
            al[mi] = *(const short8*)&sAl[r * BK + q * 8];
        }
#pragma unroll
        for (int ni = 0; ni < 4; ++ni) {
            int n = wc + ni * 16 + t;
            bh[ni] = *(const short8*)&sBh[n * BK + q * 8];
            bl[ni] = *(const short8*)&sBl[n * BK + q * 8];
        }
#pragma unroll
        for (int mi = 0; mi < 4; ++mi)
#pragma unroll
            for (int ni = 0; ni < 4; ++ni) {
                acc[mi][ni] = __builtin_amdgcn_mfma_f32_16x16x32_bf16(ah[mi], bh[ni], acc[mi][ni], 0, 0, 0);
                acc[mi][ni] = __builtin_amdgcn_mfma_f32_16x16x32_bf16(ah[mi], bl[ni], acc[mi][ni], 0, 0, 0);
                acc[mi][ni] = __builtin_amdgcn_mfma_f32_16x16x32_bf16(al[mi], bh[ni], acc[mi][ni], 0, 0, 0);
            }
        __syncthreads();
    }
#pragma unroll
    for (int mi = 0; mi < 4; ++mi) {
        int gr0 = row0 + wr + mi * 16 + q * 4;
#pragma unroll
        for (int rr = 0; rr < 4; ++rr) {
            int gr = gr0 + rr;
            if (gr < M) {
#pragma unroll
                for (int ni = 0; ni < 4; ++ni)
                    C[(size_t)gr * 256 + col0 + wc + ni * 16 + t] = acc[mi][ni][rr];
            }
        }
    }
}

// -------- stripe-parallel feature-sliced CSR gather (XCD-affine) --------
// Grid: (N_NODES/4) * 8 blocks of 256. chunk = blk&7 -> XCD blk%8; 16 feats/chunk.
// Launched twice per layer (kHalf=0: feats 0..127, kHalf=1: 128..255) so each
// XCD's resident h-slice is 50000*16*4 = 3.2 MB < 4 MB L2.
// Within a wave: stripe = lane>>2 indexes 16 neighbors in parallel; each lane
// loads a float4 (4 feats) of its neighbor's slice; butterfly-reduce stripes.
template<bool BF16OUT>
__global__ __launch_bounds__(256) void gather_sliced(
        const int* __restrict__ row_ptr, const unsigned short* __restrict__ srcs16,
        const float* __restrict__ wnorm, const float* __restrict__ dinv,
        const float* __restrict__ hW, const float* __restrict__ b,
        float* __restrict__ outF, short* __restrict__ outHi, short* __restrict__ outLo,
        int kHalf) {
    int blk = blockIdx.x;
    int chunk = blk & 7;
    int wave = threadIdx.x >> 6;
    int node = (blk >> 3) * 4 + wave;         // N_NODES % 4 == 0
    int lane = threadIdx.x & 63;
    int stripe = lane >> 2;                   // 0..15 neighbor slot
    int fq = lane & 3;                        // feat quad within slice
    int f0 = kHalf * 128 + chunk * 16 + fq * 4;

    int beg = row_ptr[node], end = row_ptr[node + 1];
    float dd = dinv[node];
    float4 acc = make_float4(0.f, 0.f, 0.f, 0.f);
    for (int cbeg = beg; cbeg < end; cbeg += 16) {
        int idx = cbeg + stripe;
        bool valid = idx < end;
        int s = valid ? (int)__builtin_nontemporal_load(&srcs16[idx]) : 0;
        float w = valid ? __builtin_nontemporal_load(&wnorm[idx]) : 0.f;
        float4 v = *(const float4*)&hW[(size_t)s * 256 + f0];
        acc.x = fmaf(v.x, w, acc.x);
        acc.y = fmaf(v.y, w, acc.y);
        acc.z = fmaf(v.z, w, acc.z);
        acc.w = fmaf(v.w, w, acc.w);
    }
    // reduce over the 16 stripes (xor on lane bits 2..5)
#pragma unroll
    for (int mask = 4; mask <= 32; mask <<= 1) {
        acc.x += __shfl_xor(acc.x, mask);
        acc.y += __shfl_xor(acc.y, mask);
        acc.z += __shfl_xor(acc.z, mask);
        acc.w += __shfl_xor(acc.w, mask);
    }
    if (stripe == 0) {   // lanes 0..3 hold the full 16-feat slice
        float4 self = *(const float4*)&hW[(size_t)node * 256 + f0];
        float4 b4 = *(const float4*)&b[f0];
        float ws = dd * dd;
        acc.x = fmaxf(fmaf(self.x, ws, acc.x) + b4.x, 0.f);
        acc.y = fmaxf(fmaf(self.y, ws, acc.y) + b4.y, 0.f);
        acc.z = fmaxf(fmaf(self.z, ws, acc.z) + b4.z, 0.f);
        acc.w = fmaxf(fmaf(self.w, ws, acc.w) + b4.w, 0.f);
        size_t o = (size_t)node * 256 + f0;
        if (BF16OUT) {
            short4v h, l;
            h.x = (short)f2bf(acc.x); l.x = (short)f2bf(acc.x - bf2f(h.x));
            h.y = (short)f2bf(acc.y); l.y = (short)f2bf(acc.y - bf2f(h.y));
            h.z = (short)f2bf(acc.z); l.z = (short)f2bf(acc.z - bf2f(h.z));
            h.w = (short)f2bf(acc.w); l.w = (short)f2bf(acc.w - bf2f(h.w));
            *(short4v*)&outHi[o] = h;
            *(short4v*)&outLo[o] = l;
        } else {
            *(float4*)&outF[o] = acc;
        }
    }
}

// ---------------- parallel triple pooling (float4, 1 wave/block) ----------------
__global__ __launch_bounds__(64) void pool_partial(
        const float* __restrict__ h, const int* __restrict__ batch,
        float* __restrict__ psum, int* __restrict__ pmaxi) {
    int g = blockIdx.x;
    int chunk = blockIdx.y;
    int lane = threadIdx.x;  // 64; lane covers feats lane*4..lane*4+3
    int lo = 0, hi = N_NODES;
    while (lo < hi) { int mid = (lo + hi) >> 1; if (batch[mid] < g) lo = mid + 1; else hi = mid; }
    int start = lo;
    lo = 0; hi = N_NODES;
    while (lo < hi) { int mid = (lo + hi) >> 1; if (batch[mid] < g + 1) lo = mid + 1; else hi = mid; }
    int end = lo;
    int len = end - start;
    if (len <= 0) return;
    int per = (len + POOL_CHUNKS - 1) / POOL_CHUNKS;
    int cs = start + chunk * per;
    int ce = cs + per; if (ce > end) ce = end;
    if (cs >= ce) return;
    const float4* hv = (const float4*)h;
    float4 sum = make_float4(0.f, 0.f, 0.f, 0.f);
    float4 mx  = make_float4(0.f, 0.f, 0.f, 0.f);
    for (int n = cs; n < ce; ++n) {
        float4 v = hv[(size_t)n * 64 + lane];
        sum.x += v.x; sum.y += v.y; sum.z += v.z; sum.w += v.w;
        mx.x = fmaxf(mx.x, v.x); mx.y = fmaxf(mx.y, v.y);
        mx.z = fmaxf(mx.z, v.z); mx.w = fmaxf(mx.w, v.w);
    }
    float* ps = &psum[g * F + lane * 4];
    atomicAdd(&ps[0], sum.x); atomicAdd(&ps[1], sum.y);
    atomicAdd(&ps[2], sum.z); atomicAdd(&ps[3], sum.w);
    int* pm = &pmaxi[g * F + lane * 4];
    atomicMax(&pm[0], __float_as_int(mx.x)); atomicMax(&pm[1], __float_as_int(mx.y));
    atomicMax(&pm[2], __float_as_int(mx.z)); atomicMax(&pm[3], __float_as_int(mx.w));
}

// ---------------- final GEMM: out[64,128] = [mean|max|sum] @ Wfc + bfc ----------------
__global__ void final_gemm(const float* __restrict__ psum, const int* __restrict__ pmaxi,
                           const int* __restrict__ batch,
                           const float* __restrict__ Wfc, const float* __restrict__ bfc,
                           float* __restrict__ out) {
    int g = blockIdx.x;   // 64
    int o = threadIdx.x;  // 128
    __shared__ float row[G_DIM];
    __shared__ int s_cnt;
    if (threadIdx.x == 0) {
        int lo = 0, hi = N_NODES;
        while (lo < hi) { int mid = (lo + hi) >> 1; if (batch[mid] < g) lo = mid + 1; else hi = mid; }
        int start = lo;
        lo = 0; hi = N_NODES;
        while (lo < hi) { int mid = (lo + hi) >> 1; if (batch[mid] < g + 1) lo = mid + 1; else hi = mid; }
        s_cnt = lo - start;
    }
    __syncthreads();
    float inv = 1.0f / fmaxf((float)s_cnt, 1.0f);
    for (int i = threadIdx.x; i < F; i += 128) {
        float s = psum[g * F + i];
        row[i]       = s * inv;
        row[F + i]   = __int_as_float(pmaxi[g * F + i]);
        row[2*F + i] = s;
    }
    __syncthreads();
    float acc = bfc[o];
    for (int k = 0; k < G_DIM; ++k) acc += row[k] * Wfc[k * F_OUT + o];
    out[g * F_OUT + o] = acc;
}

extern "C" void kernel_launch(void* const* d_in, const int* in_sizes, int n_in,
                              void* d_out, int out_size, void* d_ws, size_t ws_size,
                              hipStream_t stream) {
    const float* x    = (const float*)d_in[0];
    const int*   ei   = (const int*)d_in[1];
    const int*   batch= (const int*)d_in[2];
    const float* W1   = (const float*)d_in[4];
    const float* b1   = (const float*)d_in[5];
    const float* W2   = (const float*)d_in[6];
    const float* b2   = (const float*)d_in[7];
    const float* Wfc  = (const float*)d_in[8];
    const float* bfc  = (const float*)d_in[9];
    float* out = (float*)d_out;

    const int* src = ei;
    const int* dst = ei + N_EDGES;

    const size_t NF = (size_t)N_NODES * F;   // 12.8M

    float* bufA  = (float*)d_ws;             // [N,256] fp32 gemm out (51.2 MB)
    short* xhi   = (short*)(bufA + NF);      // [N,256] bf16 hi — reused as h1hi
    short* xlo   = xhi + NF;                 // lo — reused as h1lo
    float* h2    = (float*)xhi;              // alias: layer-2 fp32 out spans xhi+xlo
    short* w1hi  = xlo + NF;
    short* w1lo  = w1hi + 65536;
    short* w2hi  = w1lo + 65536;
    short* w2lo  = w2hi + 65536;
    float* dinv  = (float*)(w2lo + 65536);
    int*   deg   = (int*)(dinv + N_NODES);
    int*   cursor= deg + N_NODES;
    int*   row_ptr = cursor + N_NODES;
    int*   btot  = row_ptr + N_NODES + 1;
    unsigned short* srcs16 = (unsigned short*)(btot + 256);   // [E] ushort
    float* wnorm = (float*)(srcs16 + N_EDGES);                // [E] float
    float* psum  = (float*)(wnorm + N_EDGES);                 // [64][256]
    int*   pmaxi = (int*)(psum + N_GRAPHS * F);               // [64][256]

    // ---- degree + norm + CSR ----
    hipMemsetAsync(deg, 0, 2 * N_NODES * sizeof(int), stream);   // deg + cursor
    count_deg<<<(N_EDGES + 255) / 256, 256, 0, stream>>>(dst, deg);
    compute_dinv<<<(N_NODES + 255) / 256, 256, 0, stream>>>(deg, dinv);
    scan_blocks<<<SCAN_NB, 256, 0, stream>>>(deg, row_ptr, btot);
    scan_totals<<<1, 256, 0, stream>>>(btot);
    add_offsets<<<SCAN_NB, 256, 0, stream>>>(row_ptr, btot);
    bucket_edges<<<(N_EDGES + 255) / 256, 256, 0, stream>>>(src, dst, dinv, row_ptr,
                                                            cursor, srcs16, wnorm);

    // ---- casts ----
    cast_split<<<(NF / 4 + 255) / 256, 256, 0, stream>>>(x, xhi, xlo, NF / 4);
    cast_w_t<<<256, 256, 0, stream>>>(W1, w1hi, w1lo);
    cast_w_t<<<256, 256, 0, stream>>>(W2, w2hi, w2lo);

    dim3 ggrid(2, (N_NODES + BM - 1) / BM);   // (2, 391)
    int ggather = (N_NODES / 4) * 8;          // 100000 blocks

    // ---- layer 1 ----
    gemm_mfma<<<ggrid, 256, 0, stream>>>(xhi, xlo, w1hi, w1lo, bufA, N_NODES);
    gather_sliced<true><<<ggather, 256, 0, stream>>>(row_ptr, srcs16, wnorm, dinv, bufA, b1,
                                                     nullptr, xhi, xlo, 0);
    gather_sliced<true><<<ggather, 256, 0, stream>>>(row_ptr, srcs16, wnorm, dinv, bufA, b1,
                                                     nullptr, xhi, xlo, 1);

    // ---- layer 2 ----
    gemm_mfma<<<ggrid, 256, 0, stream>>>(xhi, xlo, w2hi, w2lo, bufA, N_NODES);
    gather_sliced<false><<<ggather, 256, 0, stream>>>(row_ptr, srcs16, wnorm, dinv, bufA, b2,
                                                      h2, nullptr, nullptr, 0);
    gather_sliced<false><<<ggather, 256, 0, stream>>>(row_ptr, srcs16, wnorm, dinv, bufA, b2,
                                                      h2, nullptr, nullptr, 1);

    // ---- pooling + classifier ----
    hipMemsetAsync(psum, 0, N_GRAPHS * F * 2 * sizeof(float), stream);
    pool_partial<<<dim3(N_GRAPHS, POOL_CHUNKS), 64, 0, stream>>>(h2, batch, psum, pmaxi);
    final_gemm<<<N_GRAPHS, F_OUT, 0, stream>>>(psum, pmaxi, batch, Wfc, bfc, out);
}

// Round 7
// 454.747 us; speedup vs baseline: 2.2727x; 2.2727x over previous
//
#include <hip/hip_runtime.h>

#define N_NODES 50000
#define N_EDGES 800000
#define N_GRAPHS 64
#define F 256        // F_IN == F_HID
#define F_OUT 128
#define G_DIM 768    // 3*F
#define SCAN_NB ((N_NODES + 255) / 256)   // 196
#define POOL_CHUNKS 16

typedef unsigned short ushort_t;
typedef short short8 __attribute__((ext_vector_type(8)));
typedef short short4v __attribute__((ext_vector_type(4)));
typedef unsigned short ushort8 __attribute__((ext_vector_type(8)));
typedef float float4v __attribute__((ext_vector_type(4)));

// ---- bf16 helpers (RNE) ----
__device__ __forceinline__ unsigned short f2bf(float f) {
    unsigned int u = __float_as_uint(f);
    u += 0x7FFFu + ((u >> 16) & 1u);
    return (unsigned short)(u >> 16);
}
__device__ __forceinline__ float bf2f(unsigned short s) {
    return __uint_as_float(((unsigned int)s) << 16);
}

// ---- async global->LDS, 16B per lane ----
__device__ __forceinline__ void gld_lds16(const void* gsrc, void* ldst) {
    __builtin_amdgcn_global_load_lds(
        (const __attribute__((address_space(1))) unsigned int*)gsrc,
        (__attribute__((address_space(3))) unsigned int*)ldst, 16, 0, 0);
}

// ---------------- degree count (int) ----------------
__global__ void count_deg(const int* __restrict__ dst, int* deg) {
    int e = blockIdx.x * blockDim.x + threadIdx.x;
    if (e < N_EDGES) atomicAdd(&deg[dst[e]], 1);
}

__global__ void compute_dinv(const int* __restrict__ deg, float* dinv) {
    int i = blockIdx.x * blockDim.x + threadIdx.x;
    if (i < N_NODES) dinv[i] = rsqrtf((float)(deg[i] + 1));   // +1 self-loop
}

// ---------------- 3-kernel exclusive scan over deg -> row_ptr ----------------
__global__ void scan_blocks(const int* __restrict__ deg, int* __restrict__ row_ptr,
                            int* __restrict__ block_tot) {
    __shared__ int sd[256];
    int t = threadIdx.x;
    int idx = blockIdx.x * 256 + t;
    int v = (idx < N_NODES) ? deg[idx] : 0;
    sd[t] = v;
    __syncthreads();
    for (int off = 1; off < 256; off <<= 1) {
        int a = (t >= off) ? sd[t - off] : 0;
        __syncthreads();
        sd[t] += a;
        __syncthreads();
    }
    if (idx < N_NODES) row_ptr[idx] = sd[t] - v;
    if (t == 255) block_tot[blockIdx.x] = sd[255];
}

__global__ void scan_totals(int* block_tot) {
    __shared__ int sd[256];
    int t = threadIdx.x;
    int v = (t < SCAN_NB) ? block_tot[t] : 0;
    sd[t] = v;
    __syncthreads();
    for (int off = 1; off < 256; off <<= 1) {
        int a = (t >= off) ? sd[t - off] : 0;
        __syncthreads();
        sd[t] += a;
        __syncthreads();
    }
    if (t < SCAN_NB) block_tot[t] = sd[t] - v;
}

__global__ void add_offsets(int* __restrict__ row_ptr, const int* __restrict__ block_tot) {
    int idx = blockIdx.x * 256 + threadIdx.x;
    if (idx < N_NODES) row_ptr[idx] += block_tot[blockIdx.x];
    if (idx == 0) row_ptr[N_NODES] = N_EDGES;
}

// ---------------- bucket edges into CSR order; store src idx + full norm ----------------
__global__ void bucket_edges(const int* __restrict__ src, const int* __restrict__ dst,
                             const float* __restrict__ dinv,
                             const int* __restrict__ row_ptr, int* __restrict__ cursor,
                             ushort_t* __restrict__ srcs16, float* __restrict__ wnorm) {
    int e = blockIdx.x * blockDim.x + threadIdx.x;
    if (e < N_EDGES) {
        int d = dst[e];
        int s = src[e];
        int pos = row_ptr[d] + atomicAdd(&cursor[d], 1);
        srcs16[pos] = (ushort_t)s;           // N_NODES < 65536
        wnorm[pos]  = dinv[s] * dinv[d];
    }
}

// ---------------- casts ----------------
__global__ void cast_split(const float* __restrict__ A, short* __restrict__ hi,
                           short* __restrict__ lo, int n4) {
    int i = blockIdx.x * blockDim.x + threadIdx.x;
    if (i < n4) {
        float4 v = ((const float4*)A)[i];
        short4v h, l;
        h.x = (short)f2bf(v.x); l.x = (short)f2bf(v.x - bf2f(h.x));
        h.y = (short)f2bf(v.y); l.y = (short)f2bf(v.y - bf2f(h.y));
        h.z = (short)f2bf(v.z); l.z = (short)f2bf(v.z - bf2f(h.z));
        h.w = (short)f2bf(v.w); l.w = (short)f2bf(v.w - bf2f(h.w));
        ((short4v*)hi)[i] = h;
        ((short4v*)lo)[i] = l;
    }
}

// W [256][256] -> transposed hi/lo: Bt[n][k] = W[k][n]
__global__ void cast_w_t(const float* __restrict__ W, short* __restrict__ hi,
                         short* __restrict__ lo) {
    int n = blockIdx.x;    // 256
    int k = threadIdx.x;   // 256
    float v = W[k * 256 + n];
    unsigned short h = f2bf(v);
    hi[n * 256 + k] = (short)h;
    lo[n * 256 + k] = (short)f2bf(v - bf2f(h));
}

// ---------------- split-bf16 MFMA GEMM, LDS-staged, bf16 output ----------------
// hbf[M,256] = bf16( A[M,256] @ W[256,256] );  A as hi/lo bf16, W transposed hi/lo.
#define BM 128
#define BN 128
#define BK 32
__global__ __launch_bounds__(256) void gemm_mfma(
        const short* __restrict__ Ahi, const short* __restrict__ Alo,
        const short* __restrict__ Bthi, const short* __restrict__ Btlo,
        ushort_t* __restrict__ hbf, int M) {
    __shared__ short sAh[BM * BK], sAl[BM * BK], sBh[BN * BK], sBl[BN * BK];
    int tid = threadIdx.x;
    int wave = tid >> 6, lane = tid & 63;
    int q = lane >> 4, t = lane & 15;
    int row0 = blockIdx.y * BM;
    int col0 = blockIdx.x * BN;
    int wr = (wave >> 1) * 64;
    int wc = (wave & 1) * 64;

    int lrow = lane >> 2;          // 0..15
    int lk = (lane & 3) * 8;       // k offset (shorts)
    int srow0 = wave * 32;

    float4v acc[4][4] = {};
    for (int kt = 0; kt < 256; kt += BK) {
#pragma unroll
        for (int half = 0; half < 2; ++half) {
            int r = srow0 + half * 16 + lrow;
            int ga = row0 + r; if (ga >= M) ga = M - 1;   // clamp; never stored
            size_t aoff = (size_t)ga * 256 + kt + lk;
            size_t boff = (size_t)(col0 + r) * 256 + kt + lk;
            int ldso = (srow0 + half * 16) * BK;
            gld_lds16(&Ahi[aoff], &sAh[ldso]);
            gld_lds16(&Alo[aoff], &sAl[ldso]);
            gld_lds16(&Bthi[boff], &sBh[ldso]);
            gld_lds16(&Btlo[boff], &sBl[ldso]);
        }
        __syncthreads();
        short8 ah[4], al[4], bh[4], bl[4];
#pragma unroll
        for (int mi = 0; mi < 4; ++mi) {
            int r = wr + mi * 16 + t;
            ah[mi] = *(const short8*)&sAh[r * BK + q * 8];
            al[mi] = *(const short8*)&sAl[r * BK + q * 8];
        }
#pragma unroll
        for (int ni = 0; ni < 4; ++ni) {
            int n = wc + ni * 16 + t;
            bh[ni] = *(const short8*)&sBh[n * BK + q * 8];
            bl[ni] = *(const short8*)&sBl[n * BK + q * 8];
        }
#pragma unroll
        for (int mi = 0; mi < 4; ++mi)
#pragma unroll
            for (int ni = 0; ni < 4; ++ni) {
                acc[mi][ni] = __builtin_amdgcn_mfma_f32_16x16x32_bf16(ah[mi], bh[ni], acc[mi][ni], 0, 0, 0);
                acc[mi][ni] = __builtin_amdgcn_mfma_f32_16x16x32_bf16(ah[mi], bl[ni], acc[mi][ni], 0, 0, 0);
                acc[mi][ni] = __builtin_amdgcn_mfma_f32_16x16x32_bf16(al[mi], bh[ni], acc[mi][ni], 0, 0, 0);
            }
        __syncthreads();
    }
#pragma unroll
    for (int mi = 0; mi < 4; ++mi) {
        int gr0 = row0 + wr + mi * 16 + q * 4;
#pragma unroll
        for (int rr = 0; rr < 4; ++rr) {
            int gr = gr0 + rr;
            if (gr < M) {
#pragma unroll
                for (int ni = 0; ni < 4; ++ni)
                    hbf[(size_t)gr * 256 + col0 + wc + ni * 16 + t] = f2bf(acc[mi][ni][rr]);
            }
        }
    }
}

// -------- CSR gather over bf16 h; 2 edges per wave-iteration; fused epilogue --------
// wave = node; half-wave (32 lanes x ushort8 = 512B) covers one full row.
// BF16OUT: write hi/lo split (feeds gemm2); else fp32 (feeds pooling).
template<bool BF16OUT>
__global__ __launch_bounds__(256) void gather_bf16(
        const int* __restrict__ row_ptr, const ushort_t* __restrict__ srcs16,
        const float* __restrict__ wnorm, const float* __restrict__ dinv,
        const ushort_t* __restrict__ hbf, const float* __restrict__ b,
        float* __restrict__ outF, short* __restrict__ outHi, short* __restrict__ outLo) {
    int wave = threadIdx.x >> 6;
    int node = blockIdx.x * 4 + wave;      // N_NODES % 4 == 0
    int lane = threadIdx.x & 63;
    int g = lane >> 5;                      // half-wave: which of the 2 edges
    int hl = lane & 31;                     // feats hl*8 .. hl*8+7
    int beg = row_ptr[node], end = row_ptr[node + 1];
    float dd = dinv[node];
    float acc[8] = {};
    for (int cbeg = beg; cbeg < end; cbeg += 64) {
        int n = end - cbeg; if (n > 64) n = 64;
        int sv = (lane < n) ? (int)__builtin_nontemporal_load(&srcs16[cbeg + lane]) : 0;
        float wv = (lane < n) ? __builtin_nontemporal_load(&wnorm[cbeg + lane]) : 0.f;
        for (int k = 0; k < n; k += 2) {
            int idx = k + g;                // <= 63 always; w==0 if idx>=n
            int s = __shfl(sv, idx);
            float w = __shfl(wv, idx);
            ushort8 hv = *(const ushort8*)&hbf[(size_t)s * 256 + hl * 8];
#pragma unroll
            for (int j = 0; j < 8; ++j)
                acc[j] = fmaf(bf2f(hv[j]), w, acc[j]);
        }
    }
    // combine the two half-waves
#pragma unroll
    for (int j = 0; j < 8; ++j) acc[j] += __shfl_xor(acc[j], 32);
    if (g == 0) {
        ushort8 sf = *(const ushort8*)&hbf[(size_t)node * 256 + hl * 8];
        float ws = dd * dd;
#pragma unroll
        for (int j = 0; j < 8; ++j)
            acc[j] = fmaxf(fmaf(bf2f(sf[j]), ws, acc[j]) + b[hl * 8 + j], 0.f);
        size_t o = (size_t)node * 256 + hl * 8;
        if (BF16OUT) {
            short8 h, l;
#pragma unroll
            for (int j = 0; j < 8; ++j) {
                unsigned short hh = f2bf(acc[j]);
                h[j] = (short)hh;
                l[j] = (short)f2bf(acc[j] - bf2f(hh));
            }
            *(short8*)&outHi[o] = h;
            *(short8*)&outLo[o] = l;
        } else {
            float4 v0 = make_float4(acc[0], acc[1], acc[2], acc[3]);
            float4 v1 = make_float4(acc[4], acc[5], acc[6], acc[7]);
            *(float4*)&outF[o] = v0;
            *(float4*)&outF[o + 4] = v1;
        }
    }
}

// ---------------- parallel triple pooling (float4, 1 wave/block) ----------------
__global__ __launch_bounds__(64) void pool_partial(
        const float* __restrict__ h, const int* __restrict__ batch,
        float* __restrict__ psum, int* __restrict__ pmaxi) {
    int g = blockIdx.x;
    int chunk = blockIdx.y;
    int lane = threadIdx.x;  // 64; lane covers feats lane*4..lane*4+3
    int lo = 0, hi = N_NODES;
    while (lo < hi) { int mid = (lo + hi) >> 1; if (batch[mid] < g) lo = mid + 1; else hi = mid; }
    int start = lo;
    lo = 0; hi = N_NODES;
    while (lo < hi) { int mid = (lo + hi) >> 1; if (batch[mid] < g + 1) lo = mid + 1; else hi = mid; }
    int end = lo;
    int len = end - start;
    if (len <= 0) return;
    int per = (len + POOL_CHUNKS - 1) / POOL_CHUNKS;
    int cs = start + chunk * per;
    int ce = cs + per; if (ce > end) ce = end;
    if (cs >= ce) return;
    const float4* hv = (const float4*)h;
    float4 sum = make_float4(0.f, 0.f, 0.f, 0.f);
    float4 mx  = make_float4(0.f, 0.f, 0.f, 0.f);
    for (int n = cs; n < ce; ++n) {
        float4 v = hv[(size_t)n * 64 + lane];
        sum.x += v.x; sum.y += v.y; sum.z += v.z; sum.w += v.w;
        mx.x = fmaxf(mx.x, v.x); mx.y = fmaxf(mx.y, v.y);
        mx.z = fmaxf(mx.z, v.z); mx.w = fmaxf(mx.w, v.w);
    }
    float* ps = &psum[g * F + lane * 4];
    atomicAdd(&ps[0], sum.x); atomicAdd(&ps[1], sum.y);
    atomicAdd(&ps[2], sum.z); atomicAdd(&ps[3], sum.w);
    int* pm = &pmaxi[g * F + lane * 4];
    atomicMax(&pm[0], __float_as_int(mx.x)); atomicMax(&pm[1], __float_as_int(mx.y));
    atomicMax(&pm[2], __float_as_int(mx.z)); atomicMax(&pm[3], __float_as_int(mx.w));
}

// ---------------- final GEMM: out[64,128] = [mean|max|sum] @ Wfc + bfc ----------------
__global__ void final_gemm(const float* __restrict__ psum, const int* __restrict__ pmaxi,
                           const int* __restrict__ batch,
                           const float* __restrict__ Wfc, const float* __restrict__ bfc,
                           float* __restrict__ out) {
    int g = blockIdx.x;   // 64
    int o = threadIdx.x;  // 128
    __shared__ float row[G_DIM];
    __shared__ int s_cnt;
    if (threadIdx.x == 0) {
        int lo = 0, hi = N_NODES;
        while (lo < hi) { int mid = (lo + hi) >> 1; if (batch[mid] < g) lo = mid + 1; else hi = mid; }
        int start = lo;
        lo = 0; hi = N_NODES;
        while (lo < hi) { int mid = (lo + hi) >> 1; if (batch[mid] < g + 1) lo = mid + 1; else hi = mid; }
        s_cnt = lo - start;
    }
    __syncthreads();
    float inv = 1.0f / fmaxf((float)s_cnt, 1.0f);
    for (int i = threadIdx.x; i < F; i += 128) {
        float s = psum[g * F + i];
        row[i]       = s * inv;
        row[F + i]   = __int_as_float(pmaxi[g * F + i]);
        row[2*F + i] = s;
    }
    __syncthreads();
    float acc = bfc[o];
    for (int k = 0; k < G_DIM; ++k) acc += row[k] * Wfc[k * F_OUT + o];
    out[g * F_OUT + o] = acc;
}

extern "C" void kernel_launch(void* const* d_in, const int* in_sizes, int n_in,
                              void* d_out, int out_size, void* d_ws, size_t ws_size,
                              hipStream_t stream) {
    const float* x    = (const float*)d_in[0];
    const int*   ei   = (const int*)d_in[1];
    const int*   batch= (const int*)d_in[2];
    const float* W1   = (const float*)d_in[4];
    const float* b1   = (const float*)d_in[5];
    const float* W2   = (const float*)d_in[6];
    const float* b2   = (const float*)d_in[7];
    const float* Wfc  = (const float*)d_in[8];
    const float* bfc  = (const float*)d_in[9];
    float* out = (float*)d_out;

    const int* src = ei;
    const int* dst = ei + N_EDGES;

    const size_t NF = (size_t)N_NODES * F;   // 12.8M

    ushort_t* hbf = (ushort_t*)d_ws;         // [N,256] bf16 gemm out (25.6 MB)
    short* xhi   = (short*)(hbf + NF);       // [N,256] bf16 hi — reused as h1hi (gather1 out)
    short* xlo   = xhi + NF;                 // lo — reused as h1lo
    float* h2    = (float*)xhi;              // alias: gather2 fp32 out spans xhi+xlo
    short* w1hi  = xlo + NF;
    short* w1lo  = w1hi + 65536;
    short* w2hi  = w1lo + 65536;
    short* w2lo  = w2hi + 65536;
    float* dinv  = (float*)(w2lo + 65536);
    int*   deg   = (int*)(dinv + N_NODES);
    int*   cursor= deg + N_NODES;
    int*   row_ptr = cursor + N_NODES;
    int*   btot  = row_ptr + N_NODES + 1;
    ushort_t* srcs16 = (ushort_t*)(btot + 256);   // [E] ushort
    float* wnorm = (float*)(srcs16 + N_EDGES);    // [E] float
    float* psum  = (float*)(wnorm + N_EDGES);     // [64][256]
    int*   pmaxi = (int*)(psum + N_GRAPHS * F);   // [64][256]

    // ---- degree + norm + CSR ----
    hipMemsetAsync(deg, 0, 2 * N_NODES * sizeof(int), stream);   // deg + cursor
    count_deg<<<(N_EDGES + 255) / 256, 256, 0, stream>>>(dst, deg);
    compute_dinv<<<(N_NODES + 255) / 256, 256, 0, stream>>>(deg, dinv);
    scan_blocks<<<SCAN_NB, 256, 0, stream>>>(deg, row_ptr, btot);
    scan_totals<<<1, 256, 0, stream>>>(btot);
    add_offsets<<<SCAN_NB, 256, 0, stream>>>(row_ptr, btot);
    bucket_edges<<<(N_EDGES + 255) / 256, 256, 0, stream>>>(src, dst, dinv, row_ptr,
                                                            cursor, srcs16, wnorm);

    // ---- casts ----
    cast_split<<<(NF / 4 + 255) / 256, 256, 0, stream>>>(x, xhi, xlo, NF / 4);
    cast_w_t<<<256, 256, 0, stream>>>(W1, w1hi, w1lo);
    cast_w_t<<<256, 256, 0, stream>>>(W2, w2hi, w2lo);

    dim3 ggrid(2, (N_NODES + BM - 1) / BM);   // (2, 391)
    int ngb = N_NODES / 4;                    // 12500 blocks of 4 waves

    // ---- layer 1 ----
    gemm_mfma<<<ggrid, 256, 0, stream>>>(xhi, xlo, w1hi, w1lo, hbf, N_NODES);
    gather_bf16<true><<<ngb, 256, 0, stream>>>(row_ptr, srcs16, wnorm, dinv, hbf, b1,
                                               nullptr, xhi, xlo);   // h1 -> hi/lo (x consumed)

    // ---- layer 2 ----
    gemm_mfma<<<ggrid, 256, 0, stream>>>(xhi, xlo, w2hi, w2lo, hbf, N_NODES);
    gather_bf16<false><<<ngb, 256, 0, stream>>>(row_ptr, srcs16, wnorm, dinv, hbf, b2,
                                                h2, nullptr, nullptr);   // h2 fp32

    // ---- pooling + classifier ----
    hipMemsetAsync(psum, 0, N_GRAPHS * F * 2 * sizeof(float), stream);
    pool_partial<<<dim3(N_GRAPHS, POOL_CHUNKS), 64, 0, stream>>>(h2, batch, psum, pmaxi);
    final_gemm<<<N_GRAPHS, F_OUT, 0, stream>>>(psum, pmaxi, batch, Wfc, bfc, out);
}

// Round 8
// 449.598 us; speedup vs baseline: 2.2987x; 1.0115x over previous
//
#include <hip/hip_runtime.h>

#define N_NODES 50000
#define N_EDGES 800000
#define N_GRAPHS 64
#define F 256        // F_IN == F_HID
#define F_OUT 128
#define G_DIM 768    // 3*F
#define SCAN_NB ((N_NODES + 255) / 256)   // 196
#define POOL_CHUNKS 16

typedef unsigned short ushort_t;
typedef short short8 __attribute__((ext_vector_type(8)));
typedef short short4v __attribute__((ext_vector_type(4)));
typedef unsigned short ushort8 __attribute__((ext_vector_type(8)));
typedef unsigned short ushort4v __attribute__((ext_vector_type(4)));
typedef float float4v __attribute__((ext_vector_type(4)));

// ---- bf16 helpers (RNE) ----
__device__ __forceinline__ unsigned short f2bf(float f) {
    unsigned int u = __float_as_uint(f);
    u += 0x7FFFu + ((u >> 16) & 1u);
    return (unsigned short)(u >> 16);
}
__device__ __forceinline__ float bf2f(unsigned short s) {
    return __uint_as_float(((unsigned int)s) << 16);
}

// ---- async global->LDS, 16B per lane ----
__device__ __forceinline__ void gld_lds16(const void* gsrc, void* ldst) {
    __builtin_amdgcn_global_load_lds(
        (const __attribute__((address_space(1))) unsigned int*)gsrc,
        (__attribute__((address_space(3))) unsigned int*)ldst, 16, 0, 0);
}

// ---------------- degree count (int) ----------------
__global__ void count_deg(const int* __restrict__ dst, int* deg) {
    int e = blockIdx.x * blockDim.x + threadIdx.x;
    if (e < N_EDGES) atomicAdd(&deg[dst[e]], 1);
}

// ---------------- scan blocks + fused dinv ----------------
__global__ void scan_blocks(const int* __restrict__ deg, int* __restrict__ row_ptr,
                            int* __restrict__ block_tot, float* __restrict__ dinv) {
    __shared__ int sd[256];
    int t = threadIdx.x;
    int idx = blockIdx.x * 256 + t;
    int v = (idx < N_NODES) ? deg[idx] : 0;
    if (idx < N_NODES) dinv[idx] = rsqrtf((float)(v + 1));   // +1 self-loop
    sd[t] = v;
    __syncthreads();
    for (int off = 1; off < 256; off <<= 1) {
        int a = (t >= off) ? sd[t - off] : 0;
        __syncthreads();
        sd[t] += a;
        __syncthreads();
    }
    if (idx < N_NODES) row_ptr[idx] = sd[t] - v;
    if (t == 255) block_tot[blockIdx.x] = sd[255];
}

__global__ void scan_totals(int* block_tot) {
    __shared__ int sd[256];
    int t = threadIdx.x;
    int v = (t < SCAN_NB) ? block_tot[t] : 0;
    sd[t] = v;
    __syncthreads();
    for (int off = 1; off < 256; off <<= 1) {
        int a = (t >= off) ? sd[t - off] : 0;
        __syncthreads();
        sd[t] += a;
        __syncthreads();
    }
    if (t < SCAN_NB) block_tot[t] = sd[t] - v;
}

__global__ void add_offsets(int* __restrict__ row_ptr, const int* __restrict__ block_tot) {
    int idx = blockIdx.x * 256 + threadIdx.x;
    if (idx < N_NODES) row_ptr[idx] += block_tot[blockIdx.x];
    if (idx == 0) row_ptr[N_NODES] = N_EDGES;
}

// ---------------- bucket edges into CSR order; store src idx + full norm ----------------
__global__ void bucket_edges(const int* __restrict__ src, const int* __restrict__ dst,
                             const float* __restrict__ dinv,
                             const int* __restrict__ row_ptr, int* __restrict__ cursor,
                             ushort_t* __restrict__ srcs16, float* __restrict__ wnorm) {
    int e = blockIdx.x * blockDim.x + threadIdx.x;
    if (e < N_EDGES) {
        int d = dst[e];
        int s = src[e];
        int pos = row_ptr[d] + atomicAdd(&cursor[d], 1);
        srcs16[pos] = (ushort_t)s;           // N_NODES < 65536
        wnorm[pos]  = dinv[s] * dinv[d];
    }
}

// ---------------- casts ----------------
__global__ void cast_split(const float* __restrict__ A, short* __restrict__ hi,
                           short* __restrict__ lo, int n4) {
    int i = blockIdx.x * blockDim.x + threadIdx.x;
    if (i < n4) {
        float4 v = ((const float4*)A)[i];
        short4v h, l;
        h.x = (short)f2bf(v.x); l.x = (short)f2bf(v.x - bf2f(h.x));
        h.y = (short)f2bf(v.y); l.y = (short)f2bf(v.y - bf2f(h.y));
        h.z = (short)f2bf(v.z); l.z = (short)f2bf(v.z - bf2f(h.z));
        h.w = (short)f2bf(v.w); l.w = (short)f2bf(v.w - bf2f(h.w));
        ((short4v*)hi)[i] = h;
        ((short4v*)lo)[i] = l;
    }
}

// both W1,W2 [256][256] -> transposed hi/lo in one launch (512 blocks)
__global__ void cast_w_t2(const float* __restrict__ W1, const float* __restrict__ W2,
                          short* __restrict__ hi1, short* __restrict__ lo1,
                          short* __restrict__ hi2, short* __restrict__ lo2) {
    int blk = blockIdx.x;
    const float* W = (blk < 256) ? W1 : W2;
    short* hi = (blk < 256) ? hi1 : hi2;
    short* lo = (blk < 256) ? lo1 : lo2;
    int n = blk & 255;     // 256
    int k = threadIdx.x;   // 256
    float v = W[k * 256 + n];
    unsigned short h = f2bf(v);
    hi[n * 256 + k] = (short)h;
    lo[n * 256 + k] = (short)f2bf(v - bf2f(h));
}

// ---------------- split-bf16 MFMA GEMM, LDS-staged, bf16 output ----------------
// hbf[M,256] = bf16( A[M,256] @ W[256,256] );  A as hi/lo bf16, W transposed hi/lo.
// BM=64, BN=256 (single col-block): A hi/lo read from HBM exactly once.
#define BM 64
#define BK 32
__global__ __launch_bounds__(256) void gemm_mfma(
        const short* __restrict__ Ahi, const short* __restrict__ Alo,
        const short* __restrict__ Bthi, const short* __restrict__ Btlo,
        ushort_t* __restrict__ hbf, int M) {
    __shared__ short sAh[BM * BK], sAl[BM * BK];       // 4KB + 4KB
    __shared__ short sBh[256 * BK], sBl[256 * BK];     // 16KB + 16KB
    int tid = threadIdx.x;
    int wave = tid >> 6, lane = tid & 63;
    int q = lane >> 4, t = lane & 15;
    int row0 = blockIdx.x * BM;
    int wc = wave * 64;            // wave's 64-col slice of N=256

    int lrow = lane >> 2;          // 0..15
    int lk = (lane & 3) * 8;       // k offset (shorts)

    float4v acc[4][4] = {};
    for (int kt = 0; kt < 256; kt += BK) {
        // A: wave w stages rows w*16 .. w*16+15 (1KB per array per wave)
        {
            int r = wave * 16 + lrow;
            int ga = row0 + r; if (ga >= M) ga = M - 1;   // clamp; never stored
            size_t aoff = (size_t)ga * 256 + kt + lk;
            gld_lds16(&Ahi[aoff], &sAh[wave * 512 + lane * 8]);
            gld_lds16(&Alo[aoff], &sAl[wave * 512 + lane * 8]);
        }
        // B: wave w stages n-rows w*64 .. w*64+63 (4 instrs of 16 rows each)
#pragma unroll
        for (int j = 0; j < 4; ++j) {
            int n = wave * 64 + j * 16 + lrow;
            size_t boff = (size_t)n * 256 + kt + lk;
            int ldso = wave * 2048 + j * 512 + lane * 8;
            gld_lds16(&Bthi[boff], &sBh[ldso]);
            gld_lds16(&Btlo[boff], &sBl[ldso]);
        }
        __syncthreads();
        short8 ah[4], al[4], bh[4], bl[4];
#pragma unroll
        for (int mi = 0; mi < 4; ++mi) {
            int r = mi * 16 + t;
            ah[mi] = *(const short8*)&sAh[r * BK + q * 8];
            al[mi] = *(const short8*)&sAl[r * BK + q * 8];
        }
#pragma unroll
        for (int ni = 0; ni < 4; ++ni) {
            int n = wc + ni * 16 + t;
            bh[ni] = *(const short8*)&sBh[n * BK + q * 8];
            bl[ni] = *(const short8*)&sBl[n * BK + q * 8];
        }
#pragma unroll
        for (int mi = 0; mi < 4; ++mi)
#pragma unroll
            for (int ni = 0; ni < 4; ++ni) {
                acc[mi][ni] = __builtin_amdgcn_mfma_f32_16x16x32_bf16(ah[mi], bh[ni], acc[mi][ni], 0, 0, 0);
                acc[mi][ni] = __builtin_amdgcn_mfma_f32_16x16x32_bf16(ah[mi], bl[ni], acc[mi][ni], 0, 0, 0);
                acc[mi][ni] = __builtin_amdgcn_mfma_f32_16x16x32_bf16(al[mi], bh[ni], acc[mi][ni], 0, 0, 0);
            }
        __syncthreads();
    }
#pragma unroll
    for (int mi = 0; mi < 4; ++mi) {
        int gr0 = row0 + mi * 16 + q * 4;
#pragma unroll
        for (int rr = 0; rr < 4; ++rr) {
            int gr = gr0 + rr;
            if (gr < M) {
#pragma unroll
                for (int ni = 0; ni < 4; ++ni)
                    hbf[(size_t)gr * 256 + wc + ni * 16 + t] = f2bf(acc[mi][ni][rr]);
            }
        }
    }
}

// -------- CSR gather over bf16 h; 2 edges per wave-iteration; fused epilogue --------
// wave = node; half-wave (32 lanes x ushort8 = 512B) covers one full row.
// SPLIT: write hi/lo split (feeds gemm2); else plain bf16 (feeds pooling).
template<bool SPLIT>
__global__ __launch_bounds__(256) void gather_bf16(
        const int* __restrict__ row_ptr, const ushort_t* __restrict__ srcs16,
        const float* __restrict__ wnorm, const float* __restrict__ dinv,
        const ushort_t* __restrict__ hbf, const float* __restrict__ b,
        ushort_t* __restrict__ outBf, short* __restrict__ outHi, short* __restrict__ outLo) {
    int wave = threadIdx.x >> 6;
    int node = blockIdx.x * 4 + wave;      // N_NODES % 4 == 0
    int lane = threadIdx.x & 63;
    int g = lane >> 5;                      // half-wave: which of the 2 edges
    int hl = lane & 31;                     // feats hl*8 .. hl*8+7
    int beg = row_ptr[node], end = row_ptr[node + 1];
    float dd = dinv[node];
    float acc[8] = {};
    for (int cbeg = beg; cbeg < end; cbeg += 64) {
        int n = end - cbeg; if (n > 64) n = 64;
        int sv = (lane < n) ? (int)__builtin_nontemporal_load(&srcs16[cbeg + lane]) : 0;
        float wv = (lane < n) ? __builtin_nontemporal_load(&wnorm[cbeg + lane]) : 0.f;
        for (int k = 0; k < n; k += 2) {
            int idx = k + g;                // <= 63 always; w==0 if idx>=n
            int s = __shfl(sv, idx);
            float w = __shfl(wv, idx);
            ushort8 hv = *(const ushort8*)&hbf[(size_t)s * 256 + hl * 8];
#pragma unroll
            for (int j = 0; j < 8; ++j)
                acc[j] = fmaf(bf2f(hv[j]), w, acc[j]);
        }
    }
    // combine the two half-waves
#pragma unroll
    for (int j = 0; j < 8; ++j) acc[j] += __shfl_xor(acc[j], 32);
    if (g == 0) {
        ushort8 sf = *(const ushort8*)&hbf[(size_t)node * 256 + hl * 8];
        float ws = dd * dd;
#pragma unroll
        for (int j = 0; j < 8; ++j)
            acc[j] = fmaxf(fmaf(bf2f(sf[j]), ws, acc[j]) + b[hl * 8 + j], 0.f);
        size_t o = (size_t)node * 256 + hl * 8;
        if (SPLIT) {
            short8 h, l;
#pragma unroll
            for (int j = 0; j < 8; ++j) {
                unsigned short hh = f2bf(acc[j]);
                h[j] = (short)hh;
                l[j] = (short)f2bf(acc[j] - bf2f(hh));
            }
            *(short8*)&outHi[o] = h;
            *(short8*)&outLo[o] = l;
        } else {
            ushort8 hb;
#pragma unroll
            for (int j = 0; j < 8; ++j) hb[j] = f2bf(acc[j]);
            *(ushort8*)&outBf[o] = hb;
        }
    }
}

// ---------------- parallel triple pooling over bf16 h (1 wave/block) ----------------
__global__ __launch_bounds__(64) void pool_partial(
        const ushort_t* __restrict__ h, const int* __restrict__ batch,
        float* __restrict__ psum, int* __restrict__ pmaxi) {
    int g = blockIdx.x;
    int chunk = blockIdx.y;
    int lane = threadIdx.x;  // 64; lane covers feats lane*4..lane*4+3
    int lo = 0, hi = N_NODES;
    while (lo < hi) { int mid = (lo + hi) >> 1; if (batch[mid] < g) lo = mid + 1; else hi = mid; }
    int start = lo;
    lo = 0; hi = N_NODES;
    while (lo < hi) { int mid = (lo + hi) >> 1; if (batch[mid] < g + 1) lo = mid + 1; else hi = mid; }
    int end = lo;
    int len = end - start;
    if (len <= 0) return;
    int per = (len + POOL_CHUNKS - 1) / POOL_CHUNKS;
    int cs = start + chunk * per;
    int ce = cs + per; if (ce > end) ce = end;
    if (cs >= ce) return;
    float4 sum = make_float4(0.f, 0.f, 0.f, 0.f);
    float4 mx  = make_float4(0.f, 0.f, 0.f, 0.f);
    for (int n = cs; n < ce; ++n) {
        ushort4v u = *(const ushort4v*)&h[(size_t)n * 256 + lane * 4];
        float vx = bf2f(u.x), vy = bf2f(u.y), vz = bf2f(u.z), vw = bf2f(u.w);
        sum.x += vx; sum.y += vy; sum.z += vz; sum.w += vw;
        mx.x = fmaxf(mx.x, vx); mx.y = fmaxf(mx.y, vy);
        mx.z = fmaxf(mx.z, vz); mx.w = fmaxf(mx.w, vw);
    }
    float* ps = &psum[g * F + lane * 4];
    atomicAdd(&ps[0], sum.x); atomicAdd(&ps[1], sum.y);
    atomicAdd(&ps[2], sum.z); atomicAdd(&ps[3], sum.w);
    int* pm = &pmaxi[g * F + lane * 4];
    atomicMax(&pm[0], __float_as_int(mx.x)); atomicMax(&pm[1], __float_as_int(mx.y));
    atomicMax(&pm[2], __float_as_int(mx.z)); atomicMax(&pm[3], __float_as_int(mx.w));
}

// ---------------- final GEMM: out[64,128] = [mean|max|sum] @ Wfc + bfc ----------------
__global__ void final_gemm(const float* __restrict__ psum, const int* __restrict__ pmaxi,
                           const int* __restrict__ batch,
                           const float* __restrict__ Wfc, const float* __restrict__ bfc,
                           float* __restrict__ out) {
    int g = blockIdx.x;   // 64
    int o = threadIdx.x;  // 128
    __shared__ float row[G_DIM];
    __shared__ int s_cnt;
    if (threadIdx.x == 0) {
        int lo = 0, hi = N_NODES;
        while (lo < hi) { int mid = (lo + hi) >> 1; if (batch[mid] < g) lo = mid + 1; else hi = mid; }
        int start = lo;
        lo = 0; hi = N_NODES;
        while (lo < hi) { int mid = (lo + hi) >> 1; if (batch[mid] < g + 1) lo = mid + 1; else hi = mid; }
        s_cnt = lo - start;
    }
    __syncthreads();
    float inv = 1.0f / fmaxf((float)s_cnt, 1.0f);
    for (int i = threadIdx.x; i < F; i += 128) {
        float s = psum[g * F + i];
        row[i]       = s * inv;
        row[F + i]   = __int_as_float(pmaxi[g * F + i]);
        row[2*F + i] = s;
    }
    __syncthreads();
    float acc = bfc[o];
    for (int k = 0; k < G_DIM; ++k) acc += row[k] * Wfc[k * F_OUT + o];
    out[g * F_OUT + o] = acc;
}

extern "C" void kernel_launch(void* const* d_in, const int* in_sizes, int n_in,
                              void* d_out, int out_size, void* d_ws, size_t ws_size,
                              hipStream_t stream) {
    const float* x    = (const float*)d_in[0];
    const int*   ei   = (const int*)d_in[1];
    const int*   batch= (const int*)d_in[2];
    const float* W1   = (const float*)d_in[4];
    const float* b1   = (const float*)d_in[5];
    const float* W2   = (const float*)d_in[6];
    const float* b2   = (const float*)d_in[7];
    const float* Wfc  = (const float*)d_in[8];
    const float* bfc  = (const float*)d_in[9];
    float* out = (float*)d_out;

    const int* src = ei;
    const int* dst = ei + N_EDGES;

    const size_t NF = (size_t)N_NODES * F;   // 12.8M

    ushort_t* hbf = (ushort_t*)d_ws;         // [N,256] bf16 gemm out (25.6 MB)
    short* xhi   = (short*)(hbf + NF);       // [N,256] bf16 hi — reused as h1hi (gather1 out)
    short* xlo   = xhi + NF;                 // lo — reused as h1lo
    ushort_t* h2bf = (ushort_t*)xhi;         // alias: gather2 bf16 out reuses xhi region
    short* w1hi  = xlo + NF;
    short* w1lo  = w1hi + 65536;
    short* w2hi  = w1lo + 65536;
    short* w2lo  = w2hi + 65536;
    float* dinv  = (float*)(w2lo + 65536);
    int*   deg   = (int*)(dinv + N_NODES);
    int*   cursor= deg + N_NODES;
    int*   row_ptr = cursor + N_NODES;
    int*   btot  = row_ptr + N_NODES + 1;
    ushort_t* srcs16 = (ushort_t*)(btot + 256);   // [E] ushort
    float* wnorm = (float*)(srcs16 + N_EDGES);    // [E] float
    float* psum  = (float*)(wnorm + N_EDGES);     // [64][256]
    int*   pmaxi = (int*)(psum + N_GRAPHS * F);   // [64][256]

    // ---- degree + norm + CSR ----
    hipMemsetAsync(deg, 0, 2 * N_NODES * sizeof(int), stream);   // deg + cursor
    count_deg<<<(N_EDGES + 255) / 256, 256, 0, stream>>>(dst, deg);
    scan_blocks<<<SCAN_NB, 256, 0, stream>>>(deg, row_ptr, btot, dinv);
    scan_totals<<<1, 256, 0, stream>>>(btot);
    add_offsets<<<SCAN_NB, 256, 0, stream>>>(row_ptr, btot);
    bucket_edges<<<(N_EDGES + 255) / 256, 256, 0, stream>>>(src, dst, dinv, row_ptr,
                                                            cursor, srcs16, wnorm);

    // ---- casts ----
    cast_split<<<(NF / 4 + 255) / 256, 256, 0, stream>>>(x, xhi, xlo, NF / 4);
    cast_w_t2<<<512, 256, 0, stream>>>(W1, W2, w1hi, w1lo, w2hi, w2lo);

    int ggemm = (N_NODES + BM - 1) / BM;      // 782
    int ngb = N_NODES / 4;                    // 12500 blocks of 4 waves

    // ---- layer 1 ----
    gemm_mfma<<<ggemm, 256, 0, stream>>>(xhi, xlo, w1hi, w1lo, hbf, N_NODES);
    gather_bf16<true><<<ngb, 256, 0, stream>>>(row_ptr, srcs16, wnorm, dinv, hbf, b1,
                                               nullptr, xhi, xlo);   // h1 -> hi/lo

    // ---- layer 2 ----
    gemm_mfma<<<ggemm, 256, 0, stream>>>(xhi, xlo, w2hi, w2lo, hbf, N_NODES);
    gather_bf16<false><<<ngb, 256, 0, stream>>>(row_ptr, srcs16, wnorm, dinv, hbf, b2,
                                                h2bf, nullptr, nullptr);   // h2 bf16

    // ---- pooling + classifier ----
    hipMemsetAsync(psum, 0, N_GRAPHS * F * 2 * sizeof(float), stream);
    pool_partial<<<dim3(N_GRAPHS, POOL_CHUNKS), 64, 0, stream>>>(h2bf, batch, psum, pmaxi);
    final_gemm<<<N_GRAPHS, F_OUT, 0, stream>>>(psum, pmaxi, batch, Wfc, bfc, out);
}